// Round 1
// baseline (59.736 us; speedup 1.0000x reference)
//
#include <hip/hip_runtime.h>

#define GRID_NUM 7
#define IMG_SIZE 448.0f
#define LAMBDA_COORD 5.0f
#define LAMBDA_NOOBJ 0.5f
#define NUM_CLASSES 20
#define YOLO_EPS 1e-12f

__device__ __forceinline__ float iou_pair(float px, float py, float pw, float ph,
                                          float tx, float ty, float tw, float th) {
    const float gs = IMG_SIZE / (float)GRID_NUM;  // 64.0
    float cx1 = px * gs, cy1 = py * gs, w1 = pw * IMG_SIZE, h1 = ph * IMG_SIZE;
    float cx2 = tx * gs, cy2 = ty * gs, w2 = tw * IMG_SIZE, h2 = th * IMG_SIZE;
    float ix = fmaxf(fminf(cx1 + 0.5f * w1, cx2 + 0.5f * w2) -
                     fmaxf(cx1 - 0.5f * w1, cx2 - 0.5f * w2), 0.0f);
    float iy = fmaxf(fminf(cy1 + 0.5f * h1, cy2 + 0.5f * h2) -
                     fmaxf(cy1 - 0.5f * h1, cy2 - 0.5f * h2), 0.0f);
    float inter = ix * iy;
    float uni = w1 * h1 + w2 * h2 - inter;
    return inter / (uni + YOLO_EPS);
}

__global__ void __launch_bounds__(256) yolo_loss_kernel(
        const float* __restrict__ y_pre, const float* __restrict__ y_true,
        float* __restrict__ out, int ncells, float inv_b) {
    int idx = blockIdx.x * blockDim.x + threadIdx.x;
    float acc = 0.0f;

    if (idx < ncells) {
        // y_pre cell: 30 floats, base is 8B-aligned (120B stride) -> 15 float2 loads
        const float2* p2 = reinterpret_cast<const float2*>(y_pre + (size_t)idx * 30);
        float p[30];
#pragma unroll
        for (int i = 0; i < 15; ++i) {
            float2 v = p2[i];
            p[2 * i]     = v.x;
            p[2 * i + 1] = v.y;
        }
        // y_true cell: 8 floats, 32B-aligned; need first 5
        const float* tbase = y_true + (size_t)idx * 8;
        float4 t0 = *reinterpret_cast<const float4*>(tbase);
        float gh = tbase[4];
        float cls = t0.x;
        float gx = t0.y, gy = t0.z, gw = t0.w;

        bool obj = (cls != 0.0f);

        float iou0 = iou_pair(p[0], p[1], p[2], p[3], gx, gy, gw, gh);
        float iou1 = iou_pair(p[5], p[6], p[7], p[8], gx, gy, gw, gh);
        bool c0 = iou0 > iou1;

        float l = 0.0f;
        if (obj) {
            // confidence (obj)
            float conf_pre  = c0 ? p[4] : p[9];
            float conf_true = c0 ? iou0 : iou1;
            float dc = conf_pre - conf_true;
            l += dc * dc;
            // coord
            float xp = c0 ? p[0] : p[5];
            float yp = c0 ? p[1] : p[6];
            float dx = xp - gx, dy = yp - gy;
            l += LAMBDA_COORD * (dx * dx + dy * dy);
            // scale
            float wp = c0 ? p[2] : p[7];
            float hp = c0 ? p[3] : p[8];
            float sw = sqrtf(wp + YOLO_EPS) - sqrtf(gw + YOLO_EPS);
            float sh = sqrtf(hp + YOLO_EPS) - sqrtf(gh + YOLO_EPS);
            l += LAMBDA_COORD * (sw * sw + sh * sh);
            // class
            int ci = (int)cls - 1;  // 0..19 when obj
#pragma unroll
            for (int c = 0; c < NUM_CLASSES; ++c) {
                float t = (c == ci) ? 1.0f : 0.0f;
                float dd = p[10 + c] - t;
                l += dd * dd;
            }
        } else {
            // noobj confidence
            l += LAMBDA_NOOBJ * (p[4] * p[4] + p[9] * p[9]);
        }
        acc = l * inv_b;
    }

    // wave-64 reduce
#pragma unroll
    for (int off = 32; off > 0; off >>= 1)
        acc += __shfl_down(acc, off, 64);

    __shared__ float wsum[4];  // 256 threads / 64
    int lane = threadIdx.x & 63;
    int wid  = threadIdx.x >> 6;
    if (lane == 0) wsum[wid] = acc;
    __syncthreads();
    if (threadIdx.x == 0) {
        float s = wsum[0] + wsum[1] + wsum[2] + wsum[3];
        atomicAdd(out, s);
    }
}

extern "C" void kernel_launch(void* const* d_in, const int* in_sizes, int n_in,
                              void* d_out, int out_size, void* d_ws, size_t ws_size,
                              hipStream_t stream) {
    const float* y_pre  = (const float*)d_in[0];
    const float* y_true = (const float*)d_in[1];
    float* out = (float*)d_out;

    const int B = in_sizes[0] / (GRID_NUM * GRID_NUM * 30);  // 16384
    const int ncells = B * GRID_NUM * GRID_NUM;
    const float inv_b = 1.0f / (float)B;

    hipMemsetAsync(out, 0, sizeof(float), stream);

    const int block = 256;
    const int grid = (ncells + block - 1) / block;
    yolo_loss_kernel<<<grid, block, 0, stream>>>(y_pre, y_true, out, ncells, inv_b);
}